// Round 3
// baseline (287.553 us; speedup 1.0000x reference)
//
#include <hip/hip_runtime.h>
#include <hip/hip_fp16.h>

// Problem constants (match reference)
#define NC 128
#define NS 2048
#define NX 256
#define NZ 512
#define NROWS (NX * NZ)      // 131072 output pixels
#define NCOLS (NS * NC)      // 262144 rhs rows
#define RUN 8                // contiguous nnz per lane
#define WAVE_NNZ (RUN * 64)  // 512 nnz per wave
#define NSLOTS 64            // LDS row-accumulator slots per wave

// NOTE: harness passes ALL integer inputs as int32.
// NOTE (r3): nontemporal loads on PARTIAL-LINE accesses (the 8B gathers)
//            REGRESSED (+200MB): evict-first on the table = L2 thrash.
//            Do NOT mark gathers NT.
// NOTE (r4): too-few waves (16/CU) -> occupancy-starved. Keep >=16K waves.
// NOTE (r5): per-lane GLOBAL atomics are HBM-side RMW on 8-XCD (L2s not
//            coherent): 10M atomics -> WRITE_SIZE 146MB, dep-chains of ~900cy.
//            Sink must be LDS-local; global atomics only at wave boundaries.
// NOTE (r6): FAILED theory: "VGPR-starved MLP". launch_bounds(256,4)+
//            sched_barrier left VGPR at 48, dur unchanged 150us. Per-wave
//            MLP is NOT the limiter.
// NOTE (r7): rebuilt model: 20M line transactions (16.7M random gathers +
//            3.1M stream lines) at 0.22 lines/cyc/CU = saturated miss queue
//            (Q~64 x ~500cy loaded latency). Latency is high because the
//            201MB triplet stream thrashes the 2MB rhs table out of the 4MB
//            per-XCD L2 -> gathers go to L3 (~700cy). Fix: NT (evict-first)
//            on the fully-covered read-once STREAMS, protect table in L2.
// NOTE (r8): __builtin_nontemporal_load requires clang ext_vector_type
//            operands, NOT HIP_vector_type (int4/float4) — bit-copy through
//            ext vectors.

struct alignas(8) Half4 { __half2 lo, hi; };

typedef int   vint4   __attribute__((ext_vector_type(4)));
typedef float vfloat4 __attribute__((ext_vector_type(4)));

__device__ __forceinline__ int4 nt_load_i4(const int* p) {
    vint4 t = __builtin_nontemporal_load((const vint4*)p);
    return make_int4(t.x, t.y, t.z, t.w);
}
__device__ __forceinline__ float4 nt_load_f4(const float* p) {
    vfloat4 t = __builtin_nontemporal_load((const vfloat4*)p);
    return make_float4(t.x, t.y, t.z, t.w);
}

// Kernel 1: pack x (B,K,NC,NS) into fp16 rhs[j], j = s*NC + c.
// Thread mapping: consecutive lanes = consecutive s -> coalesced reads.
// Writes are 8B at 1KB stride; stores are fire-and-forget, L2 merges.
__global__ void pack_rhs_kernel(const float* __restrict__ x,
                                Half4* __restrict__ rhs) {
    int j = blockIdx.x * blockDim.x + threadIdx.x;
    if (j >= NCOLS) return;
    int c = j >> 11;         // 0..127
    int s = j & (NS - 1);    // 0..2047, consecutive within wave
    int base = c * NS + s;   // coalesced across lanes
    Half4 h;
    h.lo = __float22half2_rn(make_float2(x[base],               x[base + 1 * NC * NS]));
    h.hi = __float22half2_rn(make_float2(x[base + 2 * NC * NS], x[base + 3 * NC * NS]));
    rhs[s * NC + c] = h;
}

__device__ __forceinline__ void global_flush(float* __restrict__ out, int r, float4 a) {
    int ix = r >> 9;          // r / NZ
    int iz = r & (NZ - 1);    // r % NZ
    int o = iz * NX + ix;     // out[b, iz, ix]
    atomicAdd(&out[0 * NROWS + o], a.x);
    atomicAdd(&out[1 * NROWS + o], a.y);
    atomicAdd(&out[2 * NROWS + o], a.z);
    atomicAdd(&out[3 * NROWS + o], a.w);
}

// Kernel 2: wave owns 512 contiguous nnz (lane: 8). Streams rows/cols/vals
// with aligned 16B NT loads (evict-first: don't thrash the rhs table out of
// L2), 8 independent fp16 gathers (normal caching: table must stay
// L2-resident), lane-local segmented accumulate flushed to per-wave LDS
// slots. Epilogue: interior rows -> direct store; 2 boundary rows -> global
// atomicAdd over memset-0 output.
__global__ void __launch_bounds__(256, 8) spmm_seg_kernel(
        const float* __restrict__ vals,
        const int* __restrict__ cols,
        const int* __restrict__ rows,
        const Half4* __restrict__ rhs,
        float* __restrict__ out,
        int nnz) {
    __shared__ float sl[4][NSLOTS][4];   // 4KB per block

    int wv   = threadIdx.x >> 6;
    int lane = threadIdx.x & 63;
    int wid  = (blockIdx.x << 2) + wv;
    int base = wid * WAVE_NNZ + lane * RUN;

    // zero this block's LDS (256 threads x 1 float4 = 4KB)
    ((float4*)sl)[threadIdx.x] = make_float4(0.f, 0.f, 0.f, 0.f);
    __syncthreads();

    // ---- stream loads: 8 nnz per lane, NT (evict-first in L2) ----
    // Issue order: cols FIRST (gather addresses depend on them).
    float4 v[2];
    int4   c4[2], r4[2];
    if (base + RUN <= nnz) {
        #pragma unroll
        for (int q = 0; q < 2; ++q) c4[q] = nt_load_i4(cols + base + 4 * q);
        #pragma unroll
        for (int q = 0; q < 2; ++q) v[q]  = nt_load_f4(vals + base + 4 * q);
        #pragma unroll
        for (int q = 0; q < 2; ++q) r4[q] = nt_load_i4(rows + base + 4 * q);
    } else {
        #pragma unroll
        for (int q = 0; q < 2; ++q) {
            #pragma unroll
            for (int k = 0; k < 4; ++k) {
                int e = base + 4 * q + k;
                int ec = e < nnz ? e : (nnz - 1);
                (&v[q].x)[k]  = e < nnz ? vals[ec] : 0.f;   // v=0: contributes nothing
                (&c4[q].x)[k] = cols[ec];
                (&r4[q].x)[k] = rows[ec];
            }
        }
    }

    // ---- 8 independent 8B gathers (L2-resident 2MB table, normal policy) ----
    Half4 g[RUN];
    #pragma unroll
    for (int q = 0; q < 2; ++q) {
        g[4 * q + 0] = rhs[c4[q].x];
        g[4 * q + 1] = rhs[c4[q].y];
        g[4 * q + 2] = rhs[c4[q].z];
        g[4 * q + 3] = rhs[c4[q].w];
    }
    // Pin: all loads issued before any consumption below.
    __builtin_amdgcn_sched_barrier(0);

    int rfirst = __shfl(r4[0].x, 0);     // wave's first row
    int rlast  = __shfl(r4[1].w, 63);    // wave's last row

    // ---- lane-local segmented accumulate, flush to LDS slots ----
    int cur = r4[0].x;
    float4 acc = make_float4(0.f, 0.f, 0.f, 0.f);
    #pragma unroll
    for (int j = 0; j < RUN; ++j) {
        int   rj = (&r4[j >> 2].x)[j & 3];
        float vj = (&v[j >> 2].x)[j & 3];
        float2 lo = __half22float2(g[j].lo);
        float2 hi = __half22float2(g[j].hi);
        if (rj != cur) {                 // rare: ~0.5 times per 8-run
            int s = cur - rfirst;
            if (s < NSLOTS) {
                atomicAdd(&sl[wv][s][0], acc.x);
                atomicAdd(&sl[wv][s][1], acc.y);
                atomicAdd(&sl[wv][s][2], acc.z);
                atomicAdd(&sl[wv][s][3], acc.w);
            } else {
                global_flush(out, cur, acc);   // span overflow: ~never
            }
            acc = make_float4(0.f, 0.f, 0.f, 0.f);
            cur = rj;
        }
        acc.x += vj * lo.x;
        acc.y += vj * lo.y;
        acc.z += vj * hi.x;
        acc.w += vj * hi.y;
    }
    {
        int s = cur - rfirst;
        if (s < NSLOTS) {
            atomicAdd(&sl[wv][s][0], acc.x);
            atomicAdd(&sl[wv][s][1], acc.y);
            atomicAdd(&sl[wv][s][2], acc.z);
            atomicAdd(&sl[wv][s][3], acc.w);
        } else {
            global_flush(out, cur, acc);
        }
    }

    __syncthreads();

    // ---- epilogue: one slot per lane ----
    int span = rlast - rfirst;
    if (lane <= span && lane < NSLOTS) {
        float ax = sl[wv][lane][0];
        float ay = sl[wv][lane][1];
        float az = sl[wv][lane][2];
        float aw = sl[wv][lane][3];
        int rr = rfirst + lane;
        int ix = rr >> 9;
        int iz = rr & (NZ - 1);
        int o = iz * NX + ix;
        if (lane == 0 || rr == rlast) {
            // boundary row: may be shared with neighbor wave
            atomicAdd(&out[0 * NROWS + o], ax);
            atomicAdd(&out[1 * NROWS + o], ay);
            atomicAdd(&out[2 * NROWS + o], az);
            atomicAdd(&out[3 * NROWS + o], aw);
        } else {
            // interior row: all its nnz are in this wave (rows sorted)
            out[0 * NROWS + o] = ax;
            out[1 * NROWS + o] = ay;
            out[2 * NROWS + o] = az;
            out[3 * NROWS + o] = aw;
        }
    }
}

// Fallback (workspace too small): inline bounds + direct fp32 gather from x.
__global__ void __launch_bounds__(256) spmm_direct_kernel(
        const float* __restrict__ x,
        const float* __restrict__ vals,
        const int* __restrict__ rows,
        const int* __restrict__ cols,
        int nnz,
        float* __restrict__ out) {
    int r = (blockIdx.x << 2) + (threadIdx.x >> 6);
    int lane = threadIdx.x & 63;
    int start, end;
    {
        int lo = 0, hi = nnz;
        while (lo < hi) { int mid = (lo + hi) >> 1; if (rows[mid] < r) lo = mid + 1; else hi = mid; }
        start = lo;
        hi = nnz;
        int key = r + 1;
        while (lo < hi) { int mid = (lo + hi) >> 1; if (rows[mid] < key) lo = mid + 1; else hi = mid; }
        end = lo;
    }
    float4 acc = {0.f, 0.f, 0.f, 0.f};
    for (int i = start + lane; i < end; i += 64) {
        float v = vals[i];
        int col = cols[i];
        int cc = col & (NC - 1);
        int ss = col >> 7;
        int b = cc * NS + ss;
        acc.x += v * x[b];
        acc.y += v * x[b + 1 * NC * NS];
        acc.z += v * x[b + 2 * NC * NS];
        acc.w += v * x[b + 3 * NC * NS];
    }
    #pragma unroll
    for (int off = 32; off >= 1; off >>= 1) {
        acc.x += __shfl_xor(acc.x, off, 64);
        acc.y += __shfl_xor(acc.y, off, 64);
        acc.z += __shfl_xor(acc.z, off, 64);
        acc.w += __shfl_xor(acc.w, off, 64);
    }
    if (lane < 4) {
        float o = (lane == 0) ? acc.x : (lane == 1) ? acc.y : (lane == 2) ? acc.z : acc.w;
        int ix = r >> 9;
        int iz = r & (NZ - 1);
        out[lane * NROWS + iz * NX + ix] = o;
    }
}

extern "C" void kernel_launch(void* const* d_in, const int* in_sizes, int n_in,
                              void* d_out, int out_size, void* d_ws, size_t ws_size,
                              hipStream_t stream) {
    const float* x        = (const float*)d_in[0];
    const float* csr_vals = (const float*)d_in[1];
    const int*   csr_rows = (const int*)d_in[2];   // int32 per harness contract
    const int*   csr_cols = (const int*)d_in[3];
    float* out = (float*)d_out;
    int nnz = in_sizes[1];

    size_t need = (size_t)NCOLS * sizeof(Half4);   // 2MB
    if (ws_size >= need) {
        Half4* rhs = (Half4*)d_ws;
        hipMemsetAsync(out, 0, (size_t)out_size * sizeof(float), stream);
        pack_rhs_kernel<<<(NCOLS + 255) / 256, 256, 0, stream>>>(x, rhs);
        int nblocks = (nnz + 4 * WAVE_NNZ - 1) / (4 * WAVE_NNZ);   // 8192 blocks, 32K waves
        spmm_seg_kernel<<<nblocks, 256, 0, stream>>>(csr_vals, csr_cols, csr_rows,
                                                     rhs, out, nnz);
    } else {
        spmm_direct_kernel<<<NROWS / 4, 256, 0, stream>>>(x, csr_vals, csr_rows, csr_cols, nnz, out);
    }
}

// Round 4
// 285.057 us; speedup vs baseline: 1.0088x; 1.0088x over previous
//
#include <hip/hip_runtime.h>
#include <hip/hip_fp16.h>

// Problem constants (match reference)
#define NC 128
#define NS 2048
#define NX 256
#define NZ 512
#define NROWS (NX * NZ)      // 131072 output pixels
#define NCOLS (NS * NC)      // 262144 rhs rows
#define RUN 8                // contiguous nnz per lane
#define WAVE_NNZ (RUN * 64)  // 512 nnz per wave
#define NSLOTS 64            // LDS row-accumulator slots per wave

// NOTE: harness passes ALL integer inputs as int32.
// NOTE (r3): nontemporal loads on PARTIAL-LINE accesses (the 8B gathers)
//            REGRESSED (+200MB): evict-first on the table = L2 thrash.
//            Do NOT mark gathers NT (L2 policy). sc0 (L1 bypass) is a
//            different axis — see r9.
// NOTE (r4): too-few waves (16/CU) -> occupancy-starved. Keep >=16K waves.
// NOTE (r5): per-lane GLOBAL atomics are HBM-side RMW on 8-XCD (L2s not
//            coherent): 10M atomics -> WRITE_SIZE 146MB, dep-chains of ~900cy.
//            Sink must be LDS-local; global atomics only at wave boundaries.
// NOTE (r6): FAILED theory: "VGPR-starved MLP". launch_bounds(256,4)+
//            sched_barrier left VGPR at 48, dur unchanged 150us. Per-wave
//            MLP is NOT the limiter.
// NOTE (r7): NT on read-once streams: FETCH 146->113MB (table stays
//            resident) but dur only 150->139us. Table residency was real
//            but not the limiter.
// NOTE (r8): __builtin_nontemporal_load requires clang ext_vector_type
//            operands, NOT HIP_vector_type (int4/float4).
// NOTE (r9): timeline shows ~5cy per gather transaction, invariant to wave
//            count and cache level = per-CU L1/TCP miss-allocation serial
//            cost (every gather is an L1 miss: random 2MB table vs 32KB L1).
//            Fix: agent-scope relaxed atomic-load on gathers -> sc0 -> L1
//            bypass, requests pipeline straight to L2.

struct alignas(8) Half4 { __half2 lo, hi; };

typedef int   vint4   __attribute__((ext_vector_type(4)));
typedef float vfloat4 __attribute__((ext_vector_type(4)));

__device__ __forceinline__ int4 nt_load_i4(const int* p) {
    vint4 t = __builtin_nontemporal_load((const vint4*)p);
    return make_int4(t.x, t.y, t.z, t.w);
}
__device__ __forceinline__ float4 nt_load_f4(const float* p) {
    vfloat4 t = __builtin_nontemporal_load((const vfloat4*)p);
    return make_float4(t.x, t.y, t.z, t.w);
}

// Gather with L1 bypass: agent-scope relaxed load emits global_load_dwordx2
// with sc0 on gfx950 — skips the CU L1 (non-coherent at agent scope), so no
// per-miss L1 allocation serialization. No fence semantics (relaxed).
__device__ __forceinline__ Half4 gather_l1bypass(const Half4* p) {
    unsigned long long raw =
        __hip_atomic_load((const unsigned long long*)p,
                          __ATOMIC_RELAXED, __HIP_MEMORY_SCOPE_AGENT);
    union { unsigned long long u; Half4 h; } cv;
    cv.u = raw;
    return cv.h;
}

// Kernel 1: pack x (B,K,NC,NS) into fp16 rhs[j], j = s*NC + c.
// Thread mapping: consecutive lanes = consecutive s -> coalesced reads.
// Writes are 8B at 1KB stride; stores are fire-and-forget, L2 merges.
__global__ void pack_rhs_kernel(const float* __restrict__ x,
                                Half4* __restrict__ rhs) {
    int j = blockIdx.x * blockDim.x + threadIdx.x;
    if (j >= NCOLS) return;
    int c = j >> 11;         // 0..127
    int s = j & (NS - 1);    // 0..2047, consecutive within wave
    int base = c * NS + s;   // coalesced across lanes
    Half4 h;
    h.lo = __float22half2_rn(make_float2(x[base],               x[base + 1 * NC * NS]));
    h.hi = __float22half2_rn(make_float2(x[base + 2 * NC * NS], x[base + 3 * NC * NS]));
    rhs[s * NC + c] = h;
}

__device__ __forceinline__ void global_flush(float* __restrict__ out, int r, float4 a) {
    int ix = r >> 9;          // r / NZ
    int iz = r & (NZ - 1);    // r % NZ
    int o = iz * NX + ix;     // out[b, iz, ix]
    atomicAdd(&out[0 * NROWS + o], a.x);
    atomicAdd(&out[1 * NROWS + o], a.y);
    atomicAdd(&out[2 * NROWS + o], a.z);
    atomicAdd(&out[3 * NROWS + o], a.w);
}

// Kernel 2: wave owns 512 contiguous nnz (lane: 8). Streams rows/cols/vals
// with aligned 16B NT loads (evict-first in L2), 8 independent fp16 gathers
// with sc0 (L1 bypass, straight to L2-resident table), lane-local segmented
// accumulate flushed to per-wave LDS slots. Epilogue: interior rows ->
// direct store; 2 boundary rows -> global atomicAdd over memset-0 output.
__global__ void __launch_bounds__(256, 8) spmm_seg_kernel(
        const float* __restrict__ vals,
        const int* __restrict__ cols,
        const int* __restrict__ rows,
        const Half4* __restrict__ rhs,
        float* __restrict__ out,
        int nnz) {
    __shared__ float sl[4][NSLOTS][4];   // 4KB per block

    int wv   = threadIdx.x >> 6;
    int lane = threadIdx.x & 63;
    int wid  = (blockIdx.x << 2) + wv;
    int base = wid * WAVE_NNZ + lane * RUN;

    // zero this block's LDS (256 threads x 1 float4 = 4KB)
    ((float4*)sl)[threadIdx.x] = make_float4(0.f, 0.f, 0.f, 0.f);
    __syncthreads();

    // ---- stream loads: 8 nnz per lane, NT (evict-first in L2) ----
    // Issue order: cols FIRST (gather addresses depend on them).
    float4 v[2];
    int4   c4[2], r4[2];
    if (base + RUN <= nnz) {
        #pragma unroll
        for (int q = 0; q < 2; ++q) c4[q] = nt_load_i4(cols + base + 4 * q);
        #pragma unroll
        for (int q = 0; q < 2; ++q) v[q]  = nt_load_f4(vals + base + 4 * q);
        #pragma unroll
        for (int q = 0; q < 2; ++q) r4[q] = nt_load_i4(rows + base + 4 * q);
    } else {
        #pragma unroll
        for (int q = 0; q < 2; ++q) {
            #pragma unroll
            for (int k = 0; k < 4; ++k) {
                int e = base + 4 * q + k;
                int ec = e < nnz ? e : (nnz - 1);
                (&v[q].x)[k]  = e < nnz ? vals[ec] : 0.f;   // v=0: contributes nothing
                (&c4[q].x)[k] = cols[ec];
                (&r4[q].x)[k] = rows[ec];
            }
        }
    }

    // ---- 8 independent 8B gathers, L1-bypass (sc0) ----
    Half4 g[RUN];
    #pragma unroll
    for (int q = 0; q < 2; ++q) {
        g[4 * q + 0] = gather_l1bypass(rhs + c4[q].x);
        g[4 * q + 1] = gather_l1bypass(rhs + c4[q].y);
        g[4 * q + 2] = gather_l1bypass(rhs + c4[q].z);
        g[4 * q + 3] = gather_l1bypass(rhs + c4[q].w);
    }
    // Pin: all loads issued before any consumption below.
    __builtin_amdgcn_sched_barrier(0);

    int rfirst = __shfl(r4[0].x, 0);     // wave's first row
    int rlast  = __shfl(r4[1].w, 63);    // wave's last row

    // ---- lane-local segmented accumulate, flush to LDS slots ----
    int cur = r4[0].x;
    float4 acc = make_float4(0.f, 0.f, 0.f, 0.f);
    #pragma unroll
    for (int j = 0; j < RUN; ++j) {
        int   rj = (&r4[j >> 2].x)[j & 3];
        float vj = (&v[j >> 2].x)[j & 3];
        float2 lo = __half22float2(g[j].lo);
        float2 hi = __half22float2(g[j].hi);
        if (rj != cur) {                 // rare: ~0.5 times per 8-run
            int s = cur - rfirst;
            if (s < NSLOTS) {
                atomicAdd(&sl[wv][s][0], acc.x);
                atomicAdd(&sl[wv][s][1], acc.y);
                atomicAdd(&sl[wv][s][2], acc.z);
                atomicAdd(&sl[wv][s][3], acc.w);
            } else {
                global_flush(out, cur, acc);   // span overflow: ~never
            }
            acc = make_float4(0.f, 0.f, 0.f, 0.f);
            cur = rj;
        }
        acc.x += vj * lo.x;
        acc.y += vj * lo.y;
        acc.z += vj * hi.x;
        acc.w += vj * hi.y;
    }
    {
        int s = cur - rfirst;
        if (s < NSLOTS) {
            atomicAdd(&sl[wv][s][0], acc.x);
            atomicAdd(&sl[wv][s][1], acc.y);
            atomicAdd(&sl[wv][s][2], acc.z);
            atomicAdd(&sl[wv][s][3], acc.w);
        } else {
            global_flush(out, cur, acc);
        }
    }

    __syncthreads();

    // ---- epilogue: one slot per lane ----
    int span = rlast - rfirst;
    if (lane <= span && lane < NSLOTS) {
        float ax = sl[wv][lane][0];
        float ay = sl[wv][lane][1];
        float az = sl[wv][lane][2];
        float aw = sl[wv][lane][3];
        int rr = rfirst + lane;
        int ix = rr >> 9;
        int iz = rr & (NZ - 1);
        int o = iz * NX + ix;
        if (lane == 0 || rr == rlast) {
            // boundary row: may be shared with neighbor wave
            atomicAdd(&out[0 * NROWS + o], ax);
            atomicAdd(&out[1 * NROWS + o], ay);
            atomicAdd(&out[2 * NROWS + o], az);
            atomicAdd(&out[3 * NROWS + o], aw);
        } else {
            // interior row: all its nnz are in this wave (rows sorted)
            out[0 * NROWS + o] = ax;
            out[1 * NROWS + o] = ay;
            out[2 * NROWS + o] = az;
            out[3 * NROWS + o] = aw;
        }
    }
}

// Fallback (workspace too small): inline bounds + direct fp32 gather from x.
__global__ void __launch_bounds__(256) spmm_direct_kernel(
        const float* __restrict__ x,
        const float* __restrict__ vals,
        const int* __restrict__ rows,
        const int* __restrict__ cols,
        int nnz,
        float* __restrict__ out) {
    int r = (blockIdx.x << 2) + (threadIdx.x >> 6);
    int lane = threadIdx.x & 63;
    int start, end;
    {
        int lo = 0, hi = nnz;
        while (lo < hi) { int mid = (lo + hi) >> 1; if (rows[mid] < r) lo = mid + 1; else hi = mid; }
        start = lo;
        hi = nnz;
        int key = r + 1;
        while (lo < hi) { int mid = (lo + hi) >> 1; if (rows[mid] < key) lo = mid + 1; else hi = mid; }
        end = lo;
    }
    float4 acc = {0.f, 0.f, 0.f, 0.f};
    for (int i = start + lane; i < end; i += 64) {
        float v = vals[i];
        int col = cols[i];
        int cc = col & (NC - 1);
        int ss = col >> 7;
        int b = cc * NS + ss;
        acc.x += v * x[b];
        acc.y += v * x[b + 1 * NC * NS];
        acc.z += v * x[b + 2 * NC * NS];
        acc.w += v * x[b + 3 * NC * NS];
    }
    #pragma unroll
    for (int off = 32; off >= 1; off >>= 1) {
        acc.x += __shfl_xor(acc.x, off, 64);
        acc.y += __shfl_xor(acc.y, off, 64);
        acc.z += __shfl_xor(acc.z, off, 64);
        acc.w += __shfl_xor(acc.w, off, 64);
    }
    if (lane < 4) {
        float o = (lane == 0) ? acc.x : (lane == 1) ? acc.y : (lane == 2) ? acc.z : acc.w;
        int ix = r >> 9;
        int iz = r & (NZ - 1);
        out[lane * NROWS + iz * NX + ix] = o;
    }
}

extern "C" void kernel_launch(void* const* d_in, const int* in_sizes, int n_in,
                              void* d_out, int out_size, void* d_ws, size_t ws_size,
                              hipStream_t stream) {
    const float* x        = (const float*)d_in[0];
    const float* csr_vals = (const float*)d_in[1];
    const int*   csr_rows = (const int*)d_in[2];   // int32 per harness contract
    const int*   csr_cols = (const int*)d_in[3];
    float* out = (float*)d_out;
    int nnz = in_sizes[1];

    size_t need = (size_t)NCOLS * sizeof(Half4);   // 2MB
    if (ws_size >= need) {
        Half4* rhs = (Half4*)d_ws;
        hipMemsetAsync(out, 0, (size_t)out_size * sizeof(float), stream);
        pack_rhs_kernel<<<(NCOLS + 255) / 256, 256, 0, stream>>>(x, rhs);
        int nblocks = (nnz + 4 * WAVE_NNZ - 1) / (4 * WAVE_NNZ);   // 8192 blocks, 32K waves
        spmm_seg_kernel<<<nblocks, 256, 0, stream>>>(csr_vals, csr_cols, csr_rows,
                                                     rhs, out, nnz);
    } else {
        spmm_direct_kernel<<<NROWS / 4, 256, 0, stream>>>(x, csr_vals, csr_rows, csr_cols, nnz, out);
    }
}